// Round 1
// baseline (664.208 us; speedup 1.0000x reference)
//
#include <hip/hip_runtime.h>
#include <hip/hip_bf16.h>
#include <math.h>

#define N_TOK 8192
#define DIM   1024
#define NEXP  16
#define TOPK  2
#define CAPE  1024
#define NSLOT (N_TOK*TOPK)

typedef __attribute__((ext_vector_type(8))) short     short8;
typedef __attribute__((ext_vector_type(4))) float     floatx4;
typedef __attribute__((ext_vector_type(4))) unsigned short ushort4v;

__device__ __forceinline__ unsigned short f2bf(float f) {
    unsigned u = __float_as_uint(f);
    u += 0x7FFFu + ((u >> 16) & 1u);   // round-to-nearest-even
    return (unsigned short)(u >> 16);
}

__device__ __forceinline__ short8 cvt8(floatx4 a, floatx4 b) {
    short8 r;
    r[0] = (short)f2bf(a[0]); r[1] = (short)f2bf(a[1]);
    r[2] = (short)f2bf(a[2]); r[3] = (short)f2bf(a[3]);
    r[4] = (short)f2bf(b[0]); r[5] = (short)f2bf(b[1]);
    r[6] = (short)f2bf(b[2]); r[7] = (short)f2bf(b[3]);
    return r;
}

// ---------------- gate: logits -> top2 -> softmax -> slot records ----------
__global__ void gate_kernel(const float* __restrict__ x,
                            const float* __restrict__ gw,
                            const float* __restrict__ gb,
                            int* __restrict__ slot_expert,
                            unsigned long long* __restrict__ slot_key,
                            float* __restrict__ slot_gate) {
    const int t    = blockIdx.x;
    const int lane = threadIdx.x;           // block = 64 = 1 wave
    float acc[NEXP];
#pragma unroll
    for (int e = 0; e < NEXP; e++) acc[e] = 0.f;
    const float* xr = x + (size_t)t * DIM;
    for (int d = lane; d < DIM; d += 64) {
        float xv = xr[d];
        const float* wr = gw + d * NEXP;
#pragma unroll
        for (int e = 0; e < NEXP; e++) acc[e] += xv * wr[e];
    }
#pragma unroll
    for (int off = 32; off > 0; off >>= 1) {
#pragma unroll
        for (int e = 0; e < NEXP; e++) acc[e] += __shfl_down(acc[e], off, 64);
    }
    if (lane == 0) {
        float v0 = -1e30f; int i0 = 0;
#pragma unroll
        for (int e = 0; e < NEXP; e++) {
            float v = acc[e] + gb[e];
            acc[e] = v;
            if (v > v0) { v0 = v; i0 = e; }   // strict > : lowest index on tie
        }
        float v1 = -1e30f; int i1 = 0;
#pragma unroll
        for (int e = 0; e < NEXP; e++) {
            if (e != i0 && acc[e] > v1) { v1 = acc[e]; i1 = e; }
        }
        float e1 = expf(v1 - v0);
        float den = 1.f + e1;
        float g0 = 1.f / den;       // max gate score (>= 0.5)
        float g1 = e1 / den;
        unsigned sb = __float_as_uint(g0);  // g0 > 0 -> bit order == float order
        int s0 = 2 * t, s1 = 2 * t + 1;
        slot_expert[s0] = i0; slot_expert[s1] = i1;
        slot_gate[s0]   = g0; slot_gate[s1]   = g1;
        unsigned long long hi = ((unsigned long long)sb) << 32;
        slot_key[s0] = hi | (unsigned)(0xFFFFFFFFu - (unsigned)s0);
        slot_key[s1] = hi | (unsigned)(0xFFFFFFFFu - (unsigned)s1);
    }
}

// ---------------- bucket fill: per-expert key lists ------------------------
__global__ void bucket_kernel(const int* __restrict__ slot_expert,
                              const unsigned long long* __restrict__ slot_key,
                              int* __restrict__ counts,
                              unsigned long long* __restrict__ buckets) {
    int s = blockIdx.x * blockDim.x + threadIdx.x;
    if (s >= NSLOT) return;
    int e = slot_expert[s];
    int p = atomicAdd(&counts[e], 1);
    buckets[(size_t)e * NSLOT + p] = slot_key[s];
}

// ---------------- keep mask + compacted expert lists -----------------------
__global__ void keep_kernel(const int* __restrict__ slot_expert,
                            const unsigned long long* __restrict__ slot_key,
                            const int* __restrict__ counts,
                            const unsigned long long* __restrict__ buckets,
                            int* __restrict__ slot_keep,
                            int* __restrict__ ecount,
                            int* __restrict__ elist) {
    int s = blockIdx.x * blockDim.x + threadIdx.x;
    if (s >= NSLOT) return;
    int e = slot_expert[s];
    int c = counts[e];
    int kp = 1;
    if (c > CAPE) {
        unsigned long long k = slot_key[s];
        const unsigned long long* bk = buckets + (size_t)e * NSLOT;
        int rank = 0;
        for (int i = 0; i < c; i++) rank += (bk[i] > k) ? 1 : 0;
        kp = (rank < CAPE) ? 1 : 0;
    }
    slot_keep[s] = kp;
    if (kp) {
        int p = atomicAdd(&ecount[e], 1);
        elist[e * CAPE + p] = s;
    }
}

// ---------------- base: out[t] = (sum of dropped gates) * x[t] -------------
__global__ void base_kernel(const float* __restrict__ x,
                            const int* __restrict__ keep,
                            const float* __restrict__ gate,
                            float* __restrict__ out) {
    int i = blockIdx.x * blockDim.x + threadIdx.x;   // float4 index
    int t = i >> 8;                                  // 256 float4 per row
    float c = 0.f;
    if (!keep[2 * t])     c += gate[2 * t];
    if (!keep[2 * t + 1]) c += gate[2 * t + 1];
    floatx4 v = ((const floatx4*)x)[i];
    ((floatx4*)out)[i] = v * c;
}

// ---------------- fp32 -> bf16 conversion ----------------------------------
__global__ void cvt_kernel(const float* __restrict__ src,
                           unsigned short* __restrict__ dst, int n4) {
    int i = blockIdx.x * blockDim.x + threadIdx.x;
    if (i >= n4) return;
    floatx4 v = ((const floatx4*)src)[i];
    ushort4v o;
    o[0] = f2bf(v[0]); o[1] = f2bf(v[1]); o[2] = f2bf(v[2]); o[3] = f2bf(v[3]);
    ((ushort4v*)dst)[i] = o;
}

// ---------------- grouped expert GEMM: out += g*(x @ W_e^T + b_e) ----------
// grid: (ntile=16, mtile=16, expert=16), block=256 (4 waves), wave = 16x64 strip
template <bool BF16IN>
__global__ __launch_bounds__(256)
void moe_gemm(const unsigned short* __restrict__ Xb,
              const float* __restrict__ Xf,
              const unsigned short* __restrict__ Wb,
              const float* __restrict__ Wf,
              const float* __restrict__ eb,
              const int* __restrict__ elist,
              const int* __restrict__ ecount,
              const float* __restrict__ slot_gate,
              float* __restrict__ out) {
    const int e  = blockIdx.z;
    const int ne = ecount[e];
    const int m0 = blockIdx.y * 64;
    if (m0 >= ne) return;
    const int n0   = blockIdx.x * 64;
    const int wv   = threadIdx.x >> 6;
    const int lane = threadIdx.x & 63;
    const int q    = lane >> 4;
    const int l15  = lane & 15;

    // A-load row for this lane (MFMA A layout: m = lane&15, k = q*8 + j)
    const int arow  = m0 + wv * 16 + l15;
    const int aslot = (arow < ne) ? elist[e * CAPE + arow] : -1;
    const int atok  = (aslot >= 0) ? (aslot >> 1) : 0;

    floatx4 acc[4] = {};
    const size_t abase = (size_t)atok * DIM + q * 8;
    const size_t wbase = (size_t)e * DIM * DIM + (size_t)q * 8;

    for (int k0 = 0; k0 < DIM; k0 += 32) {
        short8 a, b[4];
        if (BF16IN) {
            a = *(const short8*)(Xb + abase + k0);
#pragma unroll
            for (int j = 0; j < 4; j++) {
                int f = n0 + j * 16 + l15;
                b[j] = *(const short8*)(Wb + wbase + (size_t)f * DIM + k0);
            }
        } else {
            floatx4 a0 = *(const floatx4*)(Xf + abase + k0);
            floatx4 a1 = *(const floatx4*)(Xf + abase + k0 + 4);
            a = cvt8(a0, a1);
#pragma unroll
            for (int j = 0; j < 4; j++) {
                int f = n0 + j * 16 + l15;
                floatx4 b0 = *(const floatx4*)(Wf + wbase + (size_t)f * DIM + k0);
                floatx4 b1 = *(const floatx4*)(Wf + wbase + (size_t)f * DIM + k0 + 4);
                b[j] = cvt8(b0, b1);
            }
        }
#pragma unroll
        for (int j = 0; j < 4; j++)
            acc[j] = __builtin_amdgcn_mfma_f32_16x16x32_bf16(a, b[j], acc[j], 0, 0, 0);
    }

    // epilogue: C/D layout col = lane&15 (within 16-tile), row = q*4 + r
    const int erow_base = m0 + wv * 16 + q * 4;
#pragma unroll
    for (int r = 0; r < 4; r++) {
        int erow = erow_base + r;
        if (erow >= ne) continue;
        int slot = elist[e * CAPE + erow];
        int tok  = slot >> 1;
        float g  = slot_gate[slot];
#pragma unroll
        for (int j = 0; j < 4; j++) {
            int col = n0 + j * 16 + l15;
            float v = g * (acc[j][r] + eb[e * DIM + col]);
            atomicAdd(out + (size_t)tok * DIM + col, v);
        }
    }
}

extern "C" void kernel_launch(void* const* d_in, const int* in_sizes, int n_in,
                              void* d_out, int out_size, void* d_ws, size_t ws_size,
                              hipStream_t stream) {
    const float* x  = (const float*)d_in[0];   // [N, D]
    const float* gw = (const float*)d_in[1];   // [D, E]
    const float* gb = (const float*)d_in[2];   // [E]
    const float* ew = (const float*)d_in[3];   // [E, D, D]
    const float* eb = (const float*)d_in[4];   // [E, D]
    float* out = (float*)d_out;                // [N, D]

    char* ws = (char*)d_ws;
    // ---- workspace layout (offsets in bytes) ----
    int* counts = (int*)(ws + 0);                    //   64 B (16 ints)
    int* ecount = (int*)(ws + 64);                   //   64 B
    int* slot_expert = (int*)(ws + 256);             //   64 KB
    int* slot_keep   = (int*)(ws + 256 + 65536);     //   64 KB
    float* slot_gate = (float*)(ws + 256 + 131072);  //   64 KB
    unsigned long long* slot_key = (unsigned long long*)(ws + 196864);  // 128 KB
    unsigned long long* buckets  = (unsigned long long*)(ws + 327936);  //   2 MB
    int* elist = (int*)(ws + 2425088);               //   64 KB
    unsigned short* Xb = (unsigned short*)(ws + 2490624);   // 16 MB
    unsigned short* Wb = (unsigned short*)(ws + 19267840);  // 32 MB
    const size_t WS_NEED_BF16 = 52822272;

    const bool bf16path = (ws_size >= WS_NEED_BF16);

    hipMemsetAsync(ws, 0, 256, stream);  // zero counts + ecount

    gate_kernel<<<N_TOK, 64, 0, stream>>>(x, gw, gb, slot_expert, slot_key, slot_gate);
    bucket_kernel<<<NSLOT / 256, 256, 0, stream>>>(slot_expert, slot_key, counts, buckets);
    keep_kernel<<<NSLOT / 256, 256, 0, stream>>>(slot_expert, slot_key, counts, buckets,
                                                 slot_keep, ecount, elist);
    base_kernel<<<(N_TOK * DIM / 4) / 256, 256, 0, stream>>>(x, slot_keep, slot_gate, out);

    if (bf16path) {
        cvt_kernel<<<(N_TOK * DIM / 4) / 256, 256, 0, stream>>>(x, Xb, N_TOK * DIM / 4);
        cvt_kernel<<<(NEXP * DIM * DIM / 4) / 256, 256, 0, stream>>>(ew, Wb, NEXP * DIM * DIM / 4);
        moe_gemm<true><<<dim3(16, 16, 16), 256, 0, stream>>>(Xb, x, Wb, ew, eb,
                                                             elist, ecount, slot_gate, out);
    } else {
        moe_gemm<false><<<dim3(16, 16, 16), 256, 0, stream>>>(nullptr, x, nullptr, ew, eb,
                                                              elist, ecount, slot_gate, out);
    }
}

// Round 2
// 474.869 us; speedup vs baseline: 1.3987x; 1.3987x over previous
//
#include <hip/hip_runtime.h>
#include <hip/hip_bf16.h>
#include <math.h>

#define N_TOK 8192
#define DIM   1024
#define NEXP  16
#define TOPK  2
#define CAPE  1024
#define NSLOT (N_TOK*TOPK)

typedef __attribute__((ext_vector_type(8))) short     short8;
typedef __attribute__((ext_vector_type(4))) float     floatx4;
typedef __attribute__((ext_vector_type(4))) unsigned short ushort4v;

__device__ __forceinline__ unsigned short f2bf(float f) {
    unsigned u = __float_as_uint(f);
    u += 0x7FFFu + ((u >> 16) & 1u);   // round-to-nearest-even
    return (unsigned short)(u >> 16);
}

// async global->LDS, 16B per lane; LDS dest = wave-uniform base + lane*16
#define GLOAD_LDS16(g, l) __builtin_amdgcn_global_load_lds( \
    (const __attribute__((address_space(1))) unsigned int*)(g), \
    (__attribute__((address_space(3))) unsigned int*)(l), 16, 0, 0)

// ---------------- gw transpose: [D,E] -> [E,D] (64 KB, one-shot) -----------
__global__ void gwt_kernel(const float* __restrict__ gw, float* __restrict__ gwT) {
    int i = blockIdx.x * 256 + threadIdx.x;
    if (i >= DIM * NEXP) return;
    int d = i >> 4, e = i & 15;
    gwT[e * DIM + d] = gw[i];
}

// ---------------- gate: logits -> top2 -> softmax -> slot records ----------
// 4 waves/block, one token per wave, coalesced float4 reads of gwT rows.
__global__ __launch_bounds__(256) void gate_kernel(
        const float* __restrict__ x,
        const float* __restrict__ gwT,
        const float* __restrict__ gb,
        int* __restrict__ slot_expert,
        unsigned long long* __restrict__ slot_key,
        float* __restrict__ slot_gate) {
    const int t    = blockIdx.x * 4 + (threadIdx.x >> 6);
    const int lane = threadIdx.x & 63;

    const floatx4* xr = (const floatx4*)(x + (size_t)t * DIM);
    floatx4 xv[4];
#pragma unroll
    for (int i = 0; i < 4; i++) xv[i] = xr[lane + i * 64];

    float acc[NEXP];
#pragma unroll
    for (int e = 0; e < NEXP; e++) {
        const floatx4* wr = (const floatx4*)(gwT + (size_t)e * DIM);
        float a = 0.f;
#pragma unroll
        for (int i = 0; i < 4; i++) {
            floatx4 w = wr[lane + i * 64];
            a += xv[i][0]*w[0] + xv[i][1]*w[1] + xv[i][2]*w[2] + xv[i][3]*w[3];
        }
        acc[e] = a;
    }
#pragma unroll
    for (int off = 32; off > 0; off >>= 1) {
#pragma unroll
        for (int e = 0; e < NEXP; e++) acc[e] += __shfl_down(acc[e], off, 64);
    }
    if (lane == 0) {
        float v0 = -1e30f; int i0 = 0;
#pragma unroll
        for (int e = 0; e < NEXP; e++) {
            float v = acc[e] + gb[e];
            acc[e] = v;
            if (v > v0) { v0 = v; i0 = e; }   // strict > : lowest index on tie
        }
        float v1 = -1e30f; int i1 = 0;
#pragma unroll
        for (int e = 0; e < NEXP; e++) {
            if (e != i0 && acc[e] > v1) { v1 = acc[e]; i1 = e; }
        }
        float e1 = expf(v1 - v0);
        float den = 1.f + e1;
        float g0 = 1.f / den;       // max gate score (>= 0.5)
        float g1 = e1 / den;
        unsigned sb = __float_as_uint(g0);  // g0 > 0 -> bit order == float order
        int s0 = 2 * t, s1 = 2 * t + 1;
        slot_expert[s0] = i0; slot_expert[s1] = i1;
        slot_gate[s0]   = g0; slot_gate[s1]   = g1;
        unsigned long long hi = ((unsigned long long)sb) << 32;
        slot_key[s0] = hi | (unsigned)(0xFFFFFFFFu - (unsigned)s0);
        slot_key[s1] = hi | (unsigned)(0xFFFFFFFFu - (unsigned)s1);
    }
}

// ---------------- bucket fill: per-expert key lists (wave-aggregated) ------
__global__ void bucket_kernel(const int* __restrict__ slot_expert,
                              const unsigned long long* __restrict__ slot_key,
                              int* __restrict__ counts,
                              unsigned long long* __restrict__ buckets) {
    const int s = blockIdx.x * 64 + threadIdx.x;
    const int e = slot_expert[s];
    const unsigned long long key = slot_key[s];
    const int lane = threadIdx.x;
    const unsigned long long ltm = (lane == 0) ? 0ull : (~0ull >> (64 - lane));
#pragma unroll
    for (int ee = 0; ee < NEXP; ee++) {
        unsigned long long m = __ballot(e == ee);
        if (!m) continue;                      // wave-uniform
        int leader = __ffsll((unsigned long long)m) - 1;
        int base = 0;
        if (lane == leader) base = atomicAdd(&counts[ee], __popcll(m));
        base = __shfl(base, leader, 64);
        if (e == ee)
            buckets[(size_t)ee * NSLOT + base + __popcll(m & ltm)] = key;
    }
}

// ---------------- keep mask + compacted expert lists -----------------------
__global__ void keep_kernel(const int* __restrict__ slot_expert,
                            const unsigned long long* __restrict__ slot_key,
                            const int* __restrict__ counts,
                            const unsigned long long* __restrict__ buckets,
                            int* __restrict__ slot_keep,
                            int* __restrict__ ecount,
                            int* __restrict__ elist) {
    const int s = blockIdx.x * 64 + threadIdx.x;
    const int e = slot_expert[s];
    const int c = counts[e];
    int kp = 1;
    if (c > CAPE) {
        const unsigned long long k = slot_key[s];
        const unsigned long long* bk = buckets + (size_t)e * NSLOT;
        int rank = 0;
        for (int i = 0; i < c; i++) rank += (bk[i] > k) ? 1 : 0;
        kp = (rank < CAPE) ? 1 : 0;
    }
    slot_keep[s] = kp;
    const int lane = threadIdx.x;
    const unsigned long long ltm = (lane == 0) ? 0ull : (~0ull >> (64 - lane));
#pragma unroll
    for (int ee = 0; ee < NEXP; ee++) {
        unsigned long long m = __ballot(kp && e == ee);
        if (!m) continue;
        int leader = __ffsll((unsigned long long)m) - 1;
        int base = 0;
        if (lane == leader) base = atomicAdd(&ecount[ee], __popcll(m));
        base = __shfl(base, leader, 64);
        if (kp && e == ee)
            elist[ee * CAPE + base + __popcll(m & ltm)] = s;
    }
}

// ------- base: out[t] = (dropped gate sum) * x[t]; fused x->bf16 -----------
__global__ void base_kernel(const float* __restrict__ x,
                            const int* __restrict__ keep,
                            const float* __restrict__ gate,
                            float* __restrict__ out,
                            unsigned short* __restrict__ Xb) {
    int i = blockIdx.x * blockDim.x + threadIdx.x;   // float4 index
    int t = i >> 8;                                  // 256 float4 per row
    float c = 0.f;
    if (!keep[2 * t])     c += gate[2 * t];
    if (!keep[2 * t + 1]) c += gate[2 * t + 1];
    floatx4 v = ((const floatx4*)x)[i];
    ((floatx4*)out)[i] = v * c;
    ushort4v o;
    o[0] = f2bf(v[0]); o[1] = f2bf(v[1]); o[2] = f2bf(v[2]); o[3] = f2bf(v[3]);
    ((ushort4v*)Xb)[i] = o;
}

// ---------------- fp32 -> bf16 conversion (weights) ------------------------
__global__ void cvt_kernel(const float* __restrict__ src,
                           unsigned short* __restrict__ dst, int n4) {
    int i = blockIdx.x * blockDim.x + threadIdx.x;
    if (i >= n4) return;
    floatx4 v = ((const floatx4*)src)[i];
    ushort4v o;
    o[0] = f2bf(v[0]); o[1] = f2bf(v[1]); o[2] = f2bf(v[2]); o[3] = f2bf(v[3]);
    ((ushort4v*)dst)[i] = o;
}

// ---------------- grouped expert GEMM (m97 structure) ----------------------
// grid (n=8, m=8, e=16), block 256 = 4 waves; 128x128 tile, BK=32.
// LDS staging via global_load_lds width=16; A rows gathered via elist.
__global__ __launch_bounds__(256)
void moe_gemm(const unsigned short* __restrict__ Xb,
              const unsigned short* __restrict__ Wb,
              const float* __restrict__ eb,
              const int* __restrict__ elist,
              const int* __restrict__ ecount,
              const float* __restrict__ slot_gate,
              float* __restrict__ out) {
    __shared__ unsigned short As[128 * 32];   // [row][k] k-contig, 64 B rows
    __shared__ unsigned short Bs[128 * 32];

    const int e  = blockIdx.z;
    const int ne = ecount[e];
    const int m0 = blockIdx.y * 128;
    if (m0 >= ne) return;
    const int n0   = blockIdx.x * 128;
    const int wv   = threadIdx.x >> 6;
    const int lane = threadIdx.x & 63;
    const int q    = lane >> 4;
    const int l15  = lane & 15;

    // --- per-lane global base pointers for staging (K-invariant) ---
    // chunk = wv*2+c covers rows [chunk*16, chunk*16+16); lane L -> row chunk*16 + L/4,
    // k-offset (L&3)*8 bf16; LDS offset = chunk*1024B + L*16B (contiguous).
    const unsigned short* gA[2];
    const unsigned short* gB[2];
    int chunk[2];
#pragma unroll
    for (int c = 0; c < 2; c++) {
        int ch = wv * 2 + c;
        chunk[c] = ch;
        int arow = ch * 16 + (lane >> 2);
        int m    = m0 + arow;
        int slot = elist[e * CAPE + (m < ne ? m : 0)];
        int tok  = slot >> 1;
        gA[c] = Xb + (size_t)tok * DIM + (lane & 3) * 8;
        int frow = n0 + arow;
        gB[c] = Wb + (size_t)e * DIM * DIM + (size_t)frow * DIM + (lane & 3) * 8;
    }

    const int wm = (wv & 1) * 64;
    const int wn = (wv >> 1) * 64;
    floatx4 acc[4][4] = {};

    for (int k0 = 0; k0 < DIM; k0 += 32) {
        __syncthreads();   // previous iter's LDS reads done before overwrite
#pragma unroll
        for (int c = 0; c < 2; c++) {
            GLOAD_LDS16(gA[c] + k0, &As[chunk[c] * 512]);
            GLOAD_LDS16(gB[c] + k0, &Bs[chunk[c] * 512]);
        }
        __syncthreads();   // loads landed (compiler drains vmcnt before barrier)

        short8 af[4], bf[4];
#pragma unroll
        for (int fi = 0; fi < 4; fi++)
            af[fi] = *(const short8*)&As[(wm + fi * 16 + l15) * 32 + q * 8];
#pragma unroll
        for (int fj = 0; fj < 4; fj++)
            bf[fj] = *(const short8*)&Bs[(wn + fj * 16 + l15) * 32 + q * 8];
#pragma unroll
        for (int fi = 0; fi < 4; fi++)
#pragma unroll
            for (int fj = 0; fj < 4; fj++)
                acc[fi][fj] = __builtin_amdgcn_mfma_f32_16x16x32_bf16(
                    af[fi], bf[fj], acc[fi][fj], 0, 0, 0);
    }

    // --- epilogue: C/D 16x16 layout col=lane&15, row=q*4+r ---
    float ebv[4];
#pragma unroll
    for (int fj = 0; fj < 4; fj++)
        ebv[fj] = eb[e * DIM + n0 + wn + fj * 16 + l15];
#pragma unroll
    for (int fi = 0; fi < 4; fi++) {
        const int mrow = m0 + wm + fi * 16 + q * 4;
#pragma unroll
        for (int r = 0; r < 4; r++) {
            int m = mrow + r;
            if (m >= ne) continue;
            int slot = elist[e * CAPE + m];
            int tok  = slot >> 1;
            float g  = slot_gate[slot];
            float* orow = out + (size_t)tok * DIM + n0 + wn;
#pragma unroll
            for (int fj = 0; fj < 4; fj++)
                atomicAdd(orow + fj * 16 + l15, g * (acc[fi][fj][r] + ebv[fj]));
        }
    }
}

extern "C" void kernel_launch(void* const* d_in, const int* in_sizes, int n_in,
                              void* d_out, int out_size, void* d_ws, size_t ws_size,
                              hipStream_t stream) {
    const float* x  = (const float*)d_in[0];   // [N, D]
    const float* gw = (const float*)d_in[1];   // [D, E]
    const float* gb = (const float*)d_in[2];   // [E]
    const float* ew = (const float*)d_in[3];   // [E, D, D]
    const float* eb = (const float*)d_in[4];   // [E, D]
    float* out = (float*)d_out;                // [N, D]

    char* ws = (char*)d_ws;
    // ---- workspace layout (bytes) ----
    int* counts      = (int*)(ws + 0);                   //    64 B
    int* ecount      = (int*)(ws + 64);                  //    64 B
    int* slot_expert = (int*)(ws + 256);                 //  64 KB
    int* slot_keep   = (int*)(ws + 65792);               //  64 KB
    float* slot_gate = (float*)(ws + 131328);            //  64 KB
    unsigned long long* slot_key = (unsigned long long*)(ws + 196864);  // 128 KB
    unsigned long long* buckets  = (unsigned long long*)(ws + 327936);  //   2 MB
    int* elist       = (int*)(ws + 2425088);             //  64 KB
    float* gwT       = (float*)(ws + 2490624);           //  64 KB
    unsigned short* Xb = (unsigned short*)(ws + 2556160);   // 16 MB
    unsigned short* Wb = (unsigned short*)(ws + 19333376);  // 32 MB
    // total ~52.9 MB (round-1 proved ws_size covers this: bf16 path ran)

    hipMemsetAsync(ws, 0, 256, stream);  // zero counts + ecount

    gwt_kernel <<<64, 256, 0, stream>>>(gw, gwT);
    gate_kernel<<<N_TOK / 4, 256, 0, stream>>>(x, gwT, gb, slot_expert, slot_key, slot_gate);
    bucket_kernel<<<NSLOT / 64, 64, 0, stream>>>(slot_expert, slot_key, counts, buckets);
    keep_kernel<<<NSLOT / 64, 64, 0, stream>>>(slot_expert, slot_key, counts, buckets,
                                               slot_keep, ecount, elist);
    base_kernel<<<(N_TOK * DIM / 4) / 256, 256, 0, stream>>>(x, slot_keep, slot_gate, out, Xb);
    cvt_kernel<<<(NEXP * DIM * DIM / 4) / 256, 256, 0, stream>>>(ew, Wb, NEXP * DIM * DIM / 4);
    moe_gemm<<<dim3(8, 8, 16), 256, 0, stream>>>(Xb, Wb, eb, elist, ecount, slot_gate, out);
}

// Round 3
// 356.461 us; speedup vs baseline: 1.8633x; 1.3322x over previous
//
#include <hip/hip_runtime.h>
#include <hip/hip_bf16.h>
#include <math.h>

#define N_TOK 8192
#define DIM   1024
#define NEXP  16
#define TOPK  2
#define CAPE  1024
#define NSLOT (N_TOK*TOPK)

typedef __attribute__((ext_vector_type(8))) short     short8;
typedef __attribute__((ext_vector_type(4))) float     floatx4;
typedef __attribute__((ext_vector_type(4))) unsigned short ushort4v;

__device__ __forceinline__ unsigned short f2bf(float f) {
    unsigned u = __float_as_uint(f);
    u += 0x7FFFu + ((u >> 16) & 1u);   // round-to-nearest-even
    return (unsigned short)(u >> 16);
}

// async global->LDS, 16B per lane; LDS dest = wave-uniform base + lane*16
#define GLOAD_LDS16(g, l) __builtin_amdgcn_global_load_lds( \
    (const __attribute__((address_space(1))) unsigned int*)(g), \
    (__attribute__((address_space(3))) unsigned int*)(l), 16, 0, 0)

// ---------------- gw transpose: [D,E] -> [E,D] (64 KB, one-shot) -----------
__global__ void gwt_kernel(const float* __restrict__ gw, float* __restrict__ gwT) {
    int i = blockIdx.x * 256 + threadIdx.x;
    if (i >= DIM * NEXP) return;
    int d = i >> 4, e = i & 15;
    gwT[e * DIM + d] = gw[i];
}

// ------- gate: logits -> top2 -> softmax -> slot records; fused x->bf16 ----
// 4 waves/block, one token per wave, coalesced float4 reads of gwT rows.
__global__ __launch_bounds__(256) void gate_kernel(
        const float* __restrict__ x,
        const float* __restrict__ gwT,
        const float* __restrict__ gb,
        int* __restrict__ slot_expert,
        unsigned long long* __restrict__ slot_key,
        float* __restrict__ slot_gate,
        unsigned short* __restrict__ Xb) {
    const int t    = blockIdx.x * 4 + (threadIdx.x >> 6);
    const int lane = threadIdx.x & 63;

    const floatx4* xr = (const floatx4*)(x + (size_t)t * DIM);
    ushort4v* Xb4 = (ushort4v*)Xb + (size_t)t * 256;
    floatx4 xv[4];
#pragma unroll
    for (int i = 0; i < 4; i++) {
        xv[i] = xr[lane + i * 64];
        ushort4v o;
        o[0] = f2bf(xv[i][0]); o[1] = f2bf(xv[i][1]);
        o[2] = f2bf(xv[i][2]); o[3] = f2bf(xv[i][3]);
        Xb4[lane + i * 64] = o;
    }

    float acc[NEXP];
#pragma unroll
    for (int e = 0; e < NEXP; e++) {
        const floatx4* wr = (const floatx4*)(gwT + (size_t)e * DIM);
        float a = 0.f;
#pragma unroll
        for (int i = 0; i < 4; i++) {
            floatx4 w = wr[lane + i * 64];
            a += xv[i][0]*w[0] + xv[i][1]*w[1] + xv[i][2]*w[2] + xv[i][3]*w[3];
        }
        acc[e] = a;
    }
#pragma unroll
    for (int off = 32; off > 0; off >>= 1) {
#pragma unroll
        for (int e = 0; e < NEXP; e++) acc[e] += __shfl_down(acc[e], off, 64);
    }
    if (lane == 0) {
        float v0 = -1e30f; int i0 = 0;
#pragma unroll
        for (int e = 0; e < NEXP; e++) {
            float v = acc[e] + gb[e];
            acc[e] = v;
            if (v > v0) { v0 = v; i0 = e; }   // strict > : lowest index on tie
        }
        float v1 = -1e30f; int i1 = 0;
#pragma unroll
        for (int e = 0; e < NEXP; e++) {
            if (e != i0 && acc[e] > v1) { v1 = acc[e]; i1 = e; }
        }
        float e1 = expf(v1 - v0);
        float den = 1.f + e1;
        float g0 = 1.f / den;       // max gate score (>= 0.5)
        float g1 = e1 / den;
        unsigned sb = __float_as_uint(g0);  // g0 > 0 -> bit order == float order
        int s0 = 2 * t, s1 = 2 * t + 1;
        slot_expert[s0] = i0; slot_expert[s1] = i1;
        slot_gate[s0]   = g0; slot_gate[s1]   = g1;
        unsigned long long hi = ((unsigned long long)sb) << 32;
        slot_key[s0] = hi | (unsigned)(0xFFFFFFFFu - (unsigned)s0);
        slot_key[s1] = hi | (unsigned)(0xFFFFFFFFu - (unsigned)s1);
    }
}

// ---------------- bucket fill: per-expert key lists (wave-aggregated) ------
__global__ void bucket_kernel(const int* __restrict__ slot_expert,
                              const unsigned long long* __restrict__ slot_key,
                              int* __restrict__ counts,
                              unsigned long long* __restrict__ buckets) {
    const int s = blockIdx.x * 64 + threadIdx.x;
    const int e = slot_expert[s];
    const unsigned long long key = slot_key[s];
    const int lane = threadIdx.x;
    const unsigned long long ltm = (lane == 0) ? 0ull : (~0ull >> (64 - lane));
#pragma unroll
    for (int ee = 0; ee < NEXP; ee++) {
        unsigned long long m = __ballot(e == ee);
        if (!m) continue;                      // wave-uniform
        int leader = __ffsll((unsigned long long)m) - 1;
        int base = 0;
        if (lane == leader) base = atomicAdd(&counts[ee], __popcll(m));
        base = __shfl(base, leader, 64);
        if (e == ee)
            buckets[(size_t)ee * NSLOT + base + __popcll(m & ltm)] = key;
    }
}

// ---------------- keep mask: one WAVE per slot, lane-parallel rank scan ----
__global__ __launch_bounds__(256) void keep_wave_kernel(
        const int* __restrict__ slot_expert,
        const unsigned long long* __restrict__ slot_key,
        const int* __restrict__ counts,
        const unsigned long long* __restrict__ buckets,
        int* __restrict__ slot_keep) {
    const int wv   = threadIdx.x >> 6;
    const int lane = threadIdx.x & 63;
    const int s    = blockIdx.x * 4 + wv;
    const int e    = slot_expert[s];
    const int c    = counts[e];
    int kp = 1;
    if (c > CAPE) {
        const unsigned long long k = slot_key[s];
        const unsigned long long* bk = buckets + (size_t)e * NSLOT;
        int rank = 0;
        for (int i = lane; i < c; i += 64) rank += (bk[i] > k) ? 1 : 0;
#pragma unroll
        for (int off = 32; off > 0; off >>= 1) rank += __shfl_down(rank, off, 64);
        kp = (__shfl(rank, 0, 64) < CAPE) ? 1 : 0;
    }
    if (lane == 0) slot_keep[s] = kp;
}

// --------- compact: elist (+ slot_pos for ys path), wave-aggregated --------
__global__ void compact_kernel(const int* __restrict__ slot_expert,
                               const int* __restrict__ slot_keep,
                               int* __restrict__ ecount,
                               int* __restrict__ elist,
                               int* __restrict__ slot_pos) {
    const int s = blockIdx.x * 64 + threadIdx.x;
    const int e = slot_expert[s];
    const int kp = slot_keep[s];
    const int lane = threadIdx.x;
    const unsigned long long ltm = (lane == 0) ? 0ull : (~0ull >> (64 - lane));
#pragma unroll
    for (int ee = 0; ee < NEXP; ee++) {
        unsigned long long m = __ballot(kp && e == ee);
        if (!m) continue;
        int leader = __ffsll((unsigned long long)m) - 1;
        int base = 0;
        if (lane == leader) base = atomicAdd(&ecount[ee], __popcll(m));
        base = __shfl(base, leader, 64);
        if (kp && e == ee) {
            int p = base + __popcll(m & ltm);
            elist[ee * CAPE + p] = s;
            if (slot_pos) slot_pos[s] = ee * CAPE + p;
        }
    }
}

// ------- base (atomic-fallback path only): out[t] = (dropped g sum)*x[t] ---
__global__ void base_kernel(const float* __restrict__ x,
                            const int* __restrict__ keep,
                            const float* __restrict__ gate,
                            float* __restrict__ out) {
    int i = blockIdx.x * blockDim.x + threadIdx.x;   // float4 index
    int t = i >> 8;                                  // 256 float4 per row
    float c = 0.f;
    if (!keep[2 * t])     c += gate[2 * t];
    if (!keep[2 * t + 1]) c += gate[2 * t + 1];
    floatx4 v = ((const floatx4*)x)[i];
    ((floatx4*)out)[i] = v * c;
}

// ---------------- fp32 -> bf16 conversion (weights) ------------------------
__global__ void cvt_kernel(const float* __restrict__ src,
                           unsigned short* __restrict__ dst, int n4) {
    int i = blockIdx.x * blockDim.x + threadIdx.x;
    if (i >= n4) return;
    floatx4 v = ((const floatx4*)src)[i];
    ushort4v o;
    o[0] = f2bf(v[0]); o[1] = f2bf(v[1]); o[2] = f2bf(v[2]); o[3] = f2bf(v[3]);
    ((ushort4v*)dst)[i] = o;
}

// ---------------- grouped expert GEMM (m97 structure) ----------------------
// grid (n=8, m=8, e=16), block 256 = 4 waves; 128x128 tile, BK=32.
// STORE_YS: plain stores of (acc+bias) into ys[e*CAPE+m]; else atomicAdd out.
template <bool STORE_YS>
__global__ __launch_bounds__(256)
void moe_gemm(const unsigned short* __restrict__ Xb,
              const unsigned short* __restrict__ Wb,
              const float* __restrict__ eb,
              const int* __restrict__ elist,
              const int* __restrict__ ecount,
              const float* __restrict__ slot_gate,
              float* __restrict__ ys,
              float* __restrict__ out) {
    __shared__ unsigned short As[128 * 32];   // [row][k] k-contig, 64 B rows
    __shared__ unsigned short Bs[128 * 32];

    const int e  = blockIdx.z;
    const int ne = ecount[e];
    const int m0 = blockIdx.y * 128;
    if (m0 >= ne) return;
    const int n0   = blockIdx.x * 128;
    const int wv   = threadIdx.x >> 6;
    const int lane = threadIdx.x & 63;
    const int q    = lane >> 4;
    const int l15  = lane & 15;

    // --- per-lane global base pointers for staging (K-invariant) ---
    const unsigned short* gA[2];
    const unsigned short* gB[2];
    int chunk[2];
#pragma unroll
    for (int c = 0; c < 2; c++) {
        int ch = wv * 2 + c;
        chunk[c] = ch;
        int arow = ch * 16 + (lane >> 2);
        int m    = m0 + arow;
        int slot = elist[e * CAPE + (m < ne ? m : 0)];
        int tok  = slot >> 1;
        gA[c] = Xb + (size_t)tok * DIM + (lane & 3) * 8;
        int frow = n0 + arow;
        gB[c] = Wb + (size_t)e * DIM * DIM + (size_t)frow * DIM + (lane & 3) * 8;
    }

    const int wm = (wv & 1) * 64;
    const int wn = (wv >> 1) * 64;
    floatx4 acc[4][4] = {};

    for (int k0 = 0; k0 < DIM; k0 += 32) {
        __syncthreads();
#pragma unroll
        for (int c = 0; c < 2; c++) {
            GLOAD_LDS16(gA[c] + k0, &As[chunk[c] * 512]);
            GLOAD_LDS16(gB[c] + k0, &Bs[chunk[c] * 512]);
        }
        __syncthreads();

        short8 af[4], bf[4];
#pragma unroll
        for (int fi = 0; fi < 4; fi++)
            af[fi] = *(const short8*)&As[(wm + fi * 16 + l15) * 32 + q * 8];
#pragma unroll
        for (int fj = 0; fj < 4; fj++)
            bf[fj] = *(const short8*)&Bs[(wn + fj * 16 + l15) * 32 + q * 8];
#pragma unroll
        for (int fi = 0; fi < 4; fi++)
#pragma unroll
            for (int fj = 0; fj < 4; fj++)
                acc[fi][fj] = __builtin_amdgcn_mfma_f32_16x16x32_bf16(
                    af[fi], bf[fj], acc[fi][fj], 0, 0, 0);
    }

    // --- epilogue: C/D 16x16 layout col=lane&15, row=q*4+r ---
    float ebv[4];
#pragma unroll
    for (int fj = 0; fj < 4; fj++)
        ebv[fj] = eb[e * DIM + n0 + wn + fj * 16 + l15];
#pragma unroll
    for (int fi = 0; fi < 4; fi++) {
        const int mrow = m0 + wm + fi * 16 + q * 4;
#pragma unroll
        for (int r = 0; r < 4; r++) {
            int m = mrow + r;
            if (m >= ne) continue;
            if (STORE_YS) {
                float* yrow = ys + ((size_t)e * CAPE + m) * DIM + n0 + wn;
#pragma unroll
                for (int fj = 0; fj < 4; fj++)
                    yrow[fj * 16 + l15] = acc[fi][fj][r] + ebv[fj];
            } else {
                int slot = elist[e * CAPE + m];
                int tok  = slot >> 1;
                float g  = slot_gate[slot];
                float* orow = out + (size_t)tok * DIM + n0 + wn;
#pragma unroll
                for (int fj = 0; fj < 4; fj++)
                    atomicAdd(orow + fj * 16 + l15, g * (acc[fi][fj][r] + ebv[fj]));
            }
        }
    }
}

// ---------------- combine: out = sum_k g_k * (keep ? ys[pos] : x) ----------
__global__ void combine_kernel(const float* __restrict__ x,
                               const float* __restrict__ ys,
                               const int* __restrict__ keep,
                               const int* __restrict__ pos,
                               const float* __restrict__ gate,
                               float* __restrict__ out) {
    int i = blockIdx.x * 256 + threadIdx.x;   // float4 index
    int t = i >> 8;
    int c = i & 255;
    int s0 = 2 * t, s1 = s0 + 1;
    floatx4 xv = ((const floatx4*)x)[i];
    float g0 = gate[s0], g1 = gate[s1];
    floatx4 r;
    if (keep[s0]) {
        floatx4 y0 = ((const floatx4*)ys)[((size_t)pos[s0] << 8) + c];
        r = y0 * g0;
    } else r = xv * g0;
    if (keep[s1]) {
        floatx4 y1 = ((const floatx4*)ys)[((size_t)pos[s1] << 8) + c];
        r += y1 * g1;
    } else r += xv * g1;
    ((floatx4*)out)[i] = r;
}

extern "C" void kernel_launch(void* const* d_in, const int* in_sizes, int n_in,
                              void* d_out, int out_size, void* d_ws, size_t ws_size,
                              hipStream_t stream) {
    const float* x  = (const float*)d_in[0];   // [N, D]
    const float* gw = (const float*)d_in[1];   // [D, E]
    const float* gb = (const float*)d_in[2];   // [E]
    const float* ew = (const float*)d_in[3];   // [E, D, D]
    const float* eb = (const float*)d_in[4];   // [E, D]
    float* out = (float*)d_out;                // [N, D]

    char* ws = (char*)d_ws;
    // ---- workspace layout (bytes); base portion == round-2 proven layout ----
    int* counts      = (int*)(ws + 0);                   //    64 B
    int* ecount      = (int*)(ws + 64);                  //    64 B
    int* slot_expert = (int*)(ws + 256);                 //  64 KB
    int* slot_keep   = (int*)(ws + 65792);               //  64 KB
    float* slot_gate = (float*)(ws + 131328);            //  64 KB
    unsigned long long* slot_key = (unsigned long long*)(ws + 196864);  // 128 KB
    unsigned long long* buckets  = (unsigned long long*)(ws + 327936);  //   2 MB
    int* elist       = (int*)(ws + 2425088);             //  64 KB
    float* gwT       = (float*)(ws + 2490624);           //  64 KB
    unsigned short* Xb = (unsigned short*)(ws + 2556160);   // 16 MB
    unsigned short* Wb = (unsigned short*)(ws + 19333376);  // 32 MB -> end 52887808 (proven)
    int* slot_pos    = (int*)(ws + 52887808);            //  64 KB (ys path only)
    float* ys        = (float*)(ws + 52953344);          //  64 MB (ys path only)
    const size_t WS_NEED_YS = 52953344ull + (size_t)NEXP * CAPE * DIM * 4;  // ~114.5 MB

    const bool ys_path = (ws_size >= WS_NEED_YS);

    hipMemsetAsync(ws, 0, 256, stream);  // zero counts + ecount

    gwt_kernel <<<64, 256, 0, stream>>>(gw, gwT);
    gate_kernel<<<N_TOK / 4, 256, 0, stream>>>(x, gwT, gb, slot_expert, slot_key,
                                               slot_gate, Xb);
    bucket_kernel<<<NSLOT / 64, 64, 0, stream>>>(slot_expert, slot_key, counts, buckets);
    keep_wave_kernel<<<NSLOT / 4, 256, 0, stream>>>(slot_expert, slot_key, counts,
                                                    buckets, slot_keep);
    compact_kernel<<<NSLOT / 64, 64, 0, stream>>>(slot_expert, slot_keep, ecount, elist,
                                                  ys_path ? slot_pos : nullptr);
    cvt_kernel<<<(NEXP * DIM * DIM / 4) / 256, 256, 0, stream>>>(ew, Wb, NEXP * DIM * DIM / 4);

    if (ys_path) {
        moe_gemm<true><<<dim3(8, 8, 16), 256, 0, stream>>>(Xb, Wb, eb, elist, ecount,
                                                           slot_gate, ys, out);
        combine_kernel<<<N_TOK, 256, 0, stream>>>(x, ys, slot_keep, slot_pos,
                                                  slot_gate, out);
    } else {
        base_kernel<<<(N_TOK * DIM / 4) / 256, 256, 0, stream>>>(x, slot_keep,
                                                                 slot_gate, out);
        moe_gemm<false><<<dim3(8, 8, 16), 256, 0, stream>>>(Xb, Wb, eb, elist, ecount,
                                                            slot_gate, nullptr, out);
    }
}

// Round 4
// 266.836 us; speedup vs baseline: 2.4892x; 1.3359x over previous
//
#include <hip/hip_runtime.h>
#include <hip/hip_bf16.h>
#include <math.h>

#define N_TOK 8192
#define DIM   1024
#define NEXP  16
#define TOPK  2
#define CAPE  1024
#define NSLOT (N_TOK*TOPK)

typedef __attribute__((ext_vector_type(8))) short     short8;
typedef __attribute__((ext_vector_type(4))) float     floatx4;
typedef __attribute__((ext_vector_type(4))) unsigned short ushort4v;

__device__ __forceinline__ unsigned short f2bf(float f) {
    unsigned u = __float_as_uint(f);
    u += 0x7FFFu + ((u >> 16) & 1u);   // round-to-nearest-even
    return (unsigned short)(u >> 16);
}

// async global->LDS, 16B per lane; LDS dest = wave-uniform base + lane*16
#define GLOAD_LDS16(g, l) __builtin_amdgcn_global_load_lds( \
    (const __attribute__((address_space(1))) unsigned int*)(g), \
    (__attribute__((address_space(3))) unsigned int*)(l), 16, 0, 0)

// ---------------- gw transpose: [D,E] -> [E,D] (64 KB, one-shot) -----------
__global__ void gwt_kernel(const float* __restrict__ gw, float* __restrict__ gwT) {
    int i = blockIdx.x * 256 + threadIdx.x;
    if (i >= DIM * NEXP) return;
    int d = i >> 4, e = i & 15;
    gwT[e * DIM + d] = gw[i];
}

// ------- gate: logits -> top2 -> softmax -> slot records; fused x->bf16 ----
__global__ __launch_bounds__(256) void gate_kernel(
        const float* __restrict__ x,
        const float* __restrict__ gwT,
        const float* __restrict__ gb,
        int* __restrict__ slot_expert,
        unsigned long long* __restrict__ slot_key,
        float* __restrict__ slot_gate,
        unsigned short* __restrict__ Xb) {
    const int t    = blockIdx.x * 4 + (threadIdx.x >> 6);
    const int lane = threadIdx.x & 63;

    const floatx4* xr = (const floatx4*)(x + (size_t)t * DIM);
    ushort4v* Xb4 = (ushort4v*)Xb + (size_t)t * 256;
    floatx4 xv[4];
#pragma unroll
    for (int i = 0; i < 4; i++) {
        xv[i] = xr[lane + i * 64];
        ushort4v o;
        o[0] = f2bf(xv[i][0]); o[1] = f2bf(xv[i][1]);
        o[2] = f2bf(xv[i][2]); o[3] = f2bf(xv[i][3]);
        Xb4[lane + i * 64] = o;
    }

    float acc[NEXP];
#pragma unroll
    for (int e = 0; e < NEXP; e++) {
        const floatx4* wr = (const floatx4*)(gwT + (size_t)e * DIM);
        float a = 0.f;
#pragma unroll
        for (int i = 0; i < 4; i++) {
            floatx4 w = wr[lane + i * 64];
            a += xv[i][0]*w[0] + xv[i][1]*w[1] + xv[i][2]*w[2] + xv[i][3]*w[3];
        }
        acc[e] = a;
    }
#pragma unroll
    for (int off = 32; off > 0; off >>= 1) {
#pragma unroll
        for (int e = 0; e < NEXP; e++) acc[e] += __shfl_down(acc[e], off, 64);
    }
    if (lane == 0) {
        float v0 = -1e30f; int i0 = 0;
#pragma unroll
        for (int e = 0; e < NEXP; e++) {
            float v = acc[e] + gb[e];
            acc[e] = v;
            if (v > v0) { v0 = v; i0 = e; }   // strict > : lowest index on tie
        }
        float v1 = -1e30f; int i1 = 0;
#pragma unroll
        for (int e = 0; e < NEXP; e++) {
            if (e != i0 && acc[e] > v1) { v1 = acc[e]; i1 = e; }
        }
        float e1 = expf(v1 - v0);
        float den = 1.f + e1;
        float g0 = 1.f / den;       // max gate score (>= 0.5)
        float g1 = e1 / den;
        unsigned sb = __float_as_uint(g0);  // g0 > 0 -> bit order == float order
        int s0 = 2 * t, s1 = 2 * t + 1;
        slot_expert[s0] = i0; slot_expert[s1] = i1;
        slot_gate[s0]   = g0; slot_gate[s1]   = g1;
        unsigned long long hi = ((unsigned long long)sb) << 32;
        slot_key[s0] = hi | (unsigned)(0xFFFFFFFFu - (unsigned)s0);
        slot_key[s1] = hi | (unsigned)(0xFFFFFFFFu - (unsigned)s1);
    }
}

// ------- bucket fill: LDS-aggregated histogram (64 blocks x 256 thr) -------
__global__ __launch_bounds__(256) void bucket_kernel(
        const int* __restrict__ slot_expert,
        const unsigned long long* __restrict__ slot_key,
        int* __restrict__ counts,
        unsigned long long* __restrict__ buckets) {
    __shared__ int lcnt[NEXP];
    __shared__ int lbase[NEXP];
    const int tid = threadIdx.x;
    const int s = blockIdx.x * 256 + tid;
    if (tid < NEXP) lcnt[tid] = 0;
    __syncthreads();
    const int e = slot_expert[s];
    const unsigned long long key = slot_key[s];
    const int lpos = atomicAdd(&lcnt[e], 1);        // LDS atomic: cheap
    __syncthreads();
    if (tid < NEXP) lbase[tid] = lcnt[tid] ? atomicAdd(&counts[tid], lcnt[tid]) : 0;
    __syncthreads();
    buckets[(size_t)e * NSLOT + lbase[e] + lpos] = key;
}

// ---------------- keep mask: one WAVE per slot, lane-parallel rank scan ----
__global__ __launch_bounds__(256) void keep_wave_kernel(
        const int* __restrict__ slot_expert,
        const unsigned long long* __restrict__ slot_key,
        const int* __restrict__ counts,
        const unsigned long long* __restrict__ buckets,
        int* __restrict__ slot_keep) {
    const int wv   = threadIdx.x >> 6;
    const int lane = threadIdx.x & 63;
    const int s    = blockIdx.x * 4 + wv;
    const int e    = slot_expert[s];
    const int c    = counts[e];
    int kp = 1;
    if (c > CAPE) {
        const unsigned long long k = slot_key[s];
        const unsigned long long* bk = buckets + (size_t)e * NSLOT;
        int rank = 0;
        for (int i = lane; i < c; i += 64) rank += (bk[i] > k) ? 1 : 0;
#pragma unroll
        for (int off = 32; off > 0; off >>= 1) rank += __shfl_down(rank, off, 64);
        kp = (__shfl(rank, 0, 64) < CAPE) ? 1 : 0;
    }
    if (lane == 0) slot_keep[s] = kp;
}

// ---- compact: elist (+slot_pos), LDS-aggregated (64 blocks x 256 thr) -----
__global__ __launch_bounds__(256) void compact_kernel(
        const int* __restrict__ slot_expert,
        const int* __restrict__ slot_keep,
        int* __restrict__ ecount,
        int* __restrict__ elist,
        int* __restrict__ slot_pos) {
    __shared__ int lcnt[NEXP];
    __shared__ int lbase[NEXP];
    const int tid = threadIdx.x;
    const int s = blockIdx.x * 256 + tid;
    if (tid < NEXP) lcnt[tid] = 0;
    __syncthreads();
    const int e  = slot_expert[s];
    const int kp = slot_keep[s];
    int lpos = 0;
    if (kp) lpos = atomicAdd(&lcnt[e], 1);
    __syncthreads();
    if (tid < NEXP) lbase[tid] = lcnt[tid] ? atomicAdd(&ecount[tid], lcnt[tid]) : 0;
    __syncthreads();
    if (kp) {
        int p = lbase[e] + lpos;
        elist[e * CAPE + p] = s;
        if (slot_pos) slot_pos[s] = e * CAPE + p;
    }
}

// ------- base (atomic-fallback path only): out[t] = (dropped g sum)*x[t] ---
__global__ void base_kernel(const float* __restrict__ x,
                            const int* __restrict__ keep,
                            const float* __restrict__ gate,
                            float* __restrict__ out) {
    int i = blockIdx.x * blockDim.x + threadIdx.x;   // float4 index
    int t = i >> 8;                                  // 256 float4 per row
    float c = 0.f;
    if (!keep[2 * t])     c += gate[2 * t];
    if (!keep[2 * t + 1]) c += gate[2 * t + 1];
    floatx4 v = ((const floatx4*)x)[i];
    ((floatx4*)out)[i] = v * c;
}

// ---------------- fp32 -> bf16 conversion (weights) ------------------------
__global__ void cvt_kernel(const float* __restrict__ src,
                           unsigned short* __restrict__ dst, int n4) {
    int i = blockIdx.x * blockDim.x + threadIdx.x;
    if (i >= n4) return;
    floatx4 v = ((const floatx4*)src)[i];
    ushort4v o;
    o[0] = f2bf(v[0]); o[1] = f2bf(v[1]); o[2] = f2bf(v[2]); o[3] = f2bf(v[3]);
    ((ushort4v*)dst)[i] = o;
}

// ---------------- grouped expert GEMM (m97 structure + XOR swizzle) --------
// grid (n=8, m=8, e=16), block 256 = 4 waves; 128x128 tile, BK=32.
// LDS k-block position for (row, kblock q) is q ^ ((row>>1)&3): makes the
// b128 fragment reads a perfect 2-way bank spread (free) instead of 8-way.
template <bool STORE_YS>
__global__ __launch_bounds__(256)
void moe_gemm(const unsigned short* __restrict__ Xb,
              const unsigned short* __restrict__ Wb,
              const float* __restrict__ eb,
              const int* __restrict__ elist,
              const int* __restrict__ ecount,
              const float* __restrict__ slot_gate,
              float* __restrict__ ys,
              float* __restrict__ out) {
    __shared__ unsigned short As[128 * 32];   // [row][kpos] 64 B rows, swizzled
    __shared__ unsigned short Bs[128 * 32];

    const int e  = blockIdx.z;
    const int ne = ecount[e];
    const int m0 = blockIdx.y * 128;
    if (m0 >= ne) return;
    const int n0   = blockIdx.x * 128;
    const int wv   = threadIdx.x >> 6;
    const int lane = threadIdx.x & 63;
    const int q    = lane >> 4;
    const int l15  = lane & 15;

    // --- per-lane global base pointers for staging (K-invariant) ---
    // lane L -> row ch*16 + L/4; loads global kblock j = (L&3) ^ ((L>>3)&3)
    // so that LDS position (L&3) holds kblock j, i.e. pos = j ^ ((row>>1)&3).
    const int jblk = (lane & 3) ^ ((lane >> 3) & 3);
    const unsigned short* gA[2];
    const unsigned short* gB[2];
    int chunk[2];
#pragma unroll
    for (int c = 0; c < 2; c++) {
        int ch = wv * 2 + c;
        chunk[c] = ch;
        int arow = ch * 16 + (lane >> 2);
        int m    = m0 + arow;
        int slot = elist[e * CAPE + (m < ne ? m : 0)];
        int tok  = slot >> 1;
        gA[c] = Xb + (size_t)tok * DIM + jblk * 8;
        int frow = n0 + arow;
        gB[c] = Wb + (size_t)e * DIM * DIM + (size_t)frow * DIM + jblk * 8;
    }

    const int wm = (wv & 1) * 64;
    const int wn = (wv >> 1) * 64;
    const int kswz = ((l15 >> 1) & 3);   // read-side swizzle for this lane's rows
    floatx4 acc[4][4] = {};

    for (int k0 = 0; k0 < DIM; k0 += 32) {
        __syncthreads();
#pragma unroll
        for (int c = 0; c < 2; c++) {
            GLOAD_LDS16(gA[c] + k0, &As[chunk[c] * 512]);
            GLOAD_LDS16(gB[c] + k0, &Bs[chunk[c] * 512]);
        }
        __syncthreads();

        short8 af[4], bf[4];
        const int koff = (q ^ kswz) * 8;
#pragma unroll
        for (int fi = 0; fi < 4; fi++)
            af[fi] = *(const short8*)&As[(wm + fi * 16 + l15) * 32 + koff];
#pragma unroll
        for (int fj = 0; fj < 4; fj++)
            bf[fj] = *(const short8*)&Bs[(wn + fj * 16 + l15) * 32 + koff];
#pragma unroll
        for (int fi = 0; fi < 4; fi++)
#pragma unroll
            for (int fj = 0; fj < 4; fj++)
                acc[fi][fj] = __builtin_amdgcn_mfma_f32_16x16x32_bf16(
                    af[fi], bf[fj], acc[fi][fj], 0, 0, 0);
    }

    // --- epilogue: C/D 16x16 layout col=lane&15, row=q*4+r ---
    float ebv[4];
#pragma unroll
    for (int fj = 0; fj < 4; fj++)
        ebv[fj] = eb[e * DIM + n0 + wn + fj * 16 + l15];
#pragma unroll
    for (int fi = 0; fi < 4; fi++) {
        const int mrow = m0 + wm + fi * 16 + q * 4;
#pragma unroll
        for (int r = 0; r < 4; r++) {
            int m = mrow + r;
            if (m >= ne) continue;
            if (STORE_YS) {
                float* yrow = ys + ((size_t)e * CAPE + m) * DIM + n0 + wn;
#pragma unroll
                for (int fj = 0; fj < 4; fj++)
                    yrow[fj * 16 + l15] = acc[fi][fj][r] + ebv[fj];
            } else {
                int slot = elist[e * CAPE + m];
                int tok  = slot >> 1;
                float g  = slot_gate[slot];
                float* orow = out + (size_t)tok * DIM + n0 + wn;
#pragma unroll
                for (int fj = 0; fj < 4; fj++)
                    atomicAdd(orow + fj * 16 + l15, g * (acc[fi][fj][r] + ebv[fj]));
            }
        }
    }
}

// ---------------- combine: out = sum_k g_k * (keep ? ys[pos] : x) ----------
__global__ void combine_kernel(const float* __restrict__ x,
                               const float* __restrict__ ys,
                               const int* __restrict__ keep,
                               const int* __restrict__ pos,
                               const float* __restrict__ gate,
                               float* __restrict__ out) {
    int i = blockIdx.x * 256 + threadIdx.x;   // float4 index
    int t = i >> 8;
    int c = i & 255;
    int s0 = 2 * t, s1 = s0 + 1;
    floatx4 xv = ((const floatx4*)x)[i];
    float g0 = gate[s0], g1 = gate[s1];
    floatx4 r;
    if (keep[s0]) {
        floatx4 y0 = ((const floatx4*)ys)[((size_t)pos[s0] << 8) + c];
        r = y0 * g0;
    } else r = xv * g0;
    if (keep[s1]) {
        floatx4 y1 = ((const floatx4*)ys)[((size_t)pos[s1] << 8) + c];
        r += y1 * g1;
    } else r += xv * g1;
    ((floatx4*)out)[i] = r;
}

extern "C" void kernel_launch(void* const* d_in, const int* in_sizes, int n_in,
                              void* d_out, int out_size, void* d_ws, size_t ws_size,
                              hipStream_t stream) {
    const float* x  = (const float*)d_in[0];   // [N, D]
    const float* gw = (const float*)d_in[1];   // [D, E]
    const float* gb = (const float*)d_in[2];   // [E]
    const float* ew = (const float*)d_in[3];   // [E, D, D]
    const float* eb = (const float*)d_in[4];   // [E, D]
    float* out = (float*)d_out;                // [N, D]

    char* ws = (char*)d_ws;
    // ---- workspace layout (bytes); proven through round 3 ----
    int* counts      = (int*)(ws + 0);                   //    64 B
    int* ecount      = (int*)(ws + 64);                  //    64 B
    int* slot_expert = (int*)(ws + 256);                 //  64 KB
    int* slot_keep   = (int*)(ws + 65792);               //  64 KB
    float* slot_gate = (float*)(ws + 131328);            //  64 KB
    unsigned long long* slot_key = (unsigned long long*)(ws + 196864);  // 128 KB
    unsigned long long* buckets  = (unsigned long long*)(ws + 327936);  //   2 MB
    int* elist       = (int*)(ws + 2425088);             //  64 KB
    float* gwT       = (float*)(ws + 2490624);           //  64 KB
    unsigned short* Xb = (unsigned short*)(ws + 2556160);   // 16 MB
    unsigned short* Wb = (unsigned short*)(ws + 19333376);  // 32 MB -> end 52887808
    int* slot_pos    = (int*)(ws + 52887808);            //  64 KB (ys path only)
    float* ys        = (float*)(ws + 52953344);          //  64 MB (ys path only)
    const size_t WS_NEED_YS = 52953344ull + (size_t)NEXP * CAPE * DIM * 4;  // ~114.5 MB

    const bool ys_path = (ws_size >= WS_NEED_YS);

    hipMemsetAsync(ws, 0, 256, stream);  // zero counts + ecount

    gwt_kernel <<<64, 256, 0, stream>>>(gw, gwT);
    gate_kernel<<<N_TOK / 4, 256, 0, stream>>>(x, gwT, gb, slot_expert, slot_key,
                                               slot_gate, Xb);
    bucket_kernel<<<NSLOT / 256, 256, 0, stream>>>(slot_expert, slot_key, counts, buckets);
    keep_wave_kernel<<<NSLOT / 4, 256, 0, stream>>>(slot_expert, slot_key, counts,
                                                    buckets, slot_keep);
    compact_kernel<<<NSLOT / 256, 256, 0, stream>>>(slot_expert, slot_keep, ecount, elist,
                                                    ys_path ? slot_pos : nullptr);
    cvt_kernel<<<(NEXP * DIM * DIM / 4) / 256, 256, 0, stream>>>(ew, Wb, NEXP * DIM * DIM / 4);

    if (ys_path) {
        moe_gemm<true><<<dim3(8, 8, 16), 256, 0, stream>>>(Xb, Wb, eb, elist, ecount,
                                                           slot_gate, ys, out);
        combine_kernel<<<N_TOK, 256, 0, stream>>>(x, ys, slot_keep, slot_pos,
                                                  slot_gate, out);
    } else {
        base_kernel<<<(N_TOK * DIM / 4) / 256, 256, 0, stream>>>(x, slot_keep,
                                                                 slot_gate, out);
        moe_gemm<false><<<dim3(8, 8, 16), 256, 0, stream>>>(Xb, Wb, eb, elist, ecount,
                                                            slot_gate, nullptr, out);
    }
}

// Round 9
// 266.330 us; speedup vs baseline: 2.4939x; 1.0019x over previous
//
#include <hip/hip_runtime.h>
#include <hip/hip_bf16.h>
#include <math.h>

#define N_TOK 8192
#define DIM   1024
#define NEXP  16
#define TOPK  2
#define CAPE  1024
#define NSLOT (N_TOK*TOPK)

typedef __attribute__((ext_vector_type(8))) short     short8;
typedef __attribute__((ext_vector_type(4))) float     floatx4;
typedef __attribute__((ext_vector_type(4))) unsigned short ushort4v;

__device__ __forceinline__ unsigned short f2bf(float f) {
    unsigned u = __float_as_uint(f);
    u += 0x7FFFu + ((u >> 16) & 1u);   // round-to-nearest-even
    return (unsigned short)(u >> 16);
}

// async global->LDS, 16B per lane; LDS dest = wave-uniform base + lane*16
#define GLOAD_LDS16(g, l) __builtin_amdgcn_global_load_lds( \
    (const __attribute__((address_space(1))) unsigned int*)(g), \
    (__attribute__((address_space(3))) unsigned int*)(l), 16, 0, 0)

// ---------------- gw transpose: [D,E] -> [E,D] (64 KB, one-shot) -----------
__global__ void gwt_kernel(const float* __restrict__ gw, float* __restrict__ gwT) {
    int i = blockIdx.x * 256 + threadIdx.x;
    if (i >= DIM * NEXP) return;
    int d = i >> 4, e = i & 15;
    gwT[e * DIM + d] = gw[i];
}

// ------- gate: logits -> top2 -> softmax -> slot records; fused x->bf16 ----
__global__ __launch_bounds__(256) void gate_kernel(
        const float* __restrict__ x,
        const float* __restrict__ gwT,
        const float* __restrict__ gb,
        int* __restrict__ slot_expert,
        unsigned long long* __restrict__ slot_key,
        float* __restrict__ slot_gate,
        unsigned short* __restrict__ Xb) {
    const int t    = blockIdx.x * 4 + (threadIdx.x >> 6);
    const int lane = threadIdx.x & 63;

    const floatx4* xr = (const floatx4*)(x + (size_t)t * DIM);
    ushort4v* Xb4 = (ushort4v*)Xb + (size_t)t * 256;
    floatx4 xv[4];
#pragma unroll
    for (int i = 0; i < 4; i++) {
        xv[i] = xr[lane + i * 64];
        ushort4v o;
        o[0] = f2bf(xv[i][0]); o[1] = f2bf(xv[i][1]);
        o[2] = f2bf(xv[i][2]); o[3] = f2bf(xv[i][3]);
        Xb4[lane + i * 64] = o;
    }

    float acc[NEXP];
#pragma unroll
    for (int e = 0; e < NEXP; e++) {
        const floatx4* wr = (const floatx4*)(gwT + (size_t)e * DIM);
        float a = 0.f;
#pragma unroll
        for (int i = 0; i < 4; i++) {
            floatx4 w = wr[lane + i * 64];
            a += xv[i][0]*w[0] + xv[i][1]*w[1] + xv[i][2]*w[2] + xv[i][3]*w[3];
        }
        acc[e] = a;
    }
#pragma unroll
    for (int off = 32; off > 0; off >>= 1) {
#pragma unroll
        for (int e = 0; e < NEXP; e++) acc[e] += __shfl_down(acc[e], off, 64);
    }
    if (lane == 0) {
        float v0 = -1e30f; int i0 = 0;
#pragma unroll
        for (int e = 0; e < NEXP; e++) {
            float v = acc[e] + gb[e];
            acc[e] = v;
            if (v > v0) { v0 = v; i0 = e; }   // strict > : lowest index on tie
        }
        float v1 = -1e30f; int i1 = 0;
#pragma unroll
        for (int e = 0; e < NEXP; e++) {
            if (e != i0 && acc[e] > v1) { v1 = acc[e]; i1 = e; }
        }
        float e1 = expf(v1 - v0);
        float den = 1.f + e1;
        float g0 = 1.f / den;       // max gate score (>= 0.5)
        float g1 = e1 / den;
        unsigned sb = __float_as_uint(g0);  // g0 > 0 -> bit order == float order
        int s0 = 2 * t, s1 = 2 * t + 1;
        slot_expert[s0] = i0; slot_expert[s1] = i1;
        slot_gate[s0]   = g0; slot_gate[s1]   = g1;
        unsigned long long hi = ((unsigned long long)sb) << 32;
        slot_key[s0] = hi | (unsigned)(0xFFFFFFFFu - (unsigned)s0);
        slot_key[s1] = hi | (unsigned)(0xFFFFFFFFu - (unsigned)s1);
    }
}

// ------- bucket fill: LDS-aggregated histogram (64 blocks x 256 thr) -------
__global__ __launch_bounds__(256) void bucket_kernel(
        const int* __restrict__ slot_expert,
        const unsigned long long* __restrict__ slot_key,
        int* __restrict__ counts,
        unsigned long long* __restrict__ buckets) {
    __shared__ int lcnt[NEXP];
    __shared__ int lbase[NEXP];
    const int tid = threadIdx.x;
    const int s = blockIdx.x * 256 + tid;
    if (tid < NEXP) lcnt[tid] = 0;
    __syncthreads();
    const int e = slot_expert[s];
    const unsigned long long key = slot_key[s];
    const int lpos = atomicAdd(&lcnt[e], 1);        // LDS atomic: cheap
    __syncthreads();
    if (tid < NEXP) lbase[tid] = lcnt[tid] ? atomicAdd(&counts[tid], lcnt[tid]) : 0;
    __syncthreads();
    buckets[(size_t)e * NSLOT + lbase[e] + lpos] = key;
}

// ---------------- keep mask: one WAVE per slot, lane-parallel rank scan ----
__global__ __launch_bounds__(256) void keep_wave_kernel(
        const int* __restrict__ slot_expert,
        const unsigned long long* __restrict__ slot_key,
        const int* __restrict__ counts,
        const unsigned long long* __restrict__ buckets,
        int* __restrict__ slot_keep) {
    const int wv   = threadIdx.x >> 6;
    const int lane = threadIdx.x & 63;
    const int s    = blockIdx.x * 4 + wv;
    const int e    = slot_expert[s];
    const int c    = counts[e];
    int kp = 1;
    if (c > CAPE) {
        const unsigned long long k = slot_key[s];
        const unsigned long long* bk = buckets + (size_t)e * NSLOT;
        int rank = 0;
        for (int i = lane; i < c; i += 64) rank += (bk[i] > k) ? 1 : 0;
#pragma unroll
        for (int off = 32; off > 0; off >>= 1) rank += __shfl_down(rank, off, 64);
        kp = (__shfl(rank, 0, 64) < CAPE) ? 1 : 0;
    }
    if (lane == 0) slot_keep[s] = kp;
}

// ---- compact: elist (+slot_pos), LDS-aggregated (64 blocks x 256 thr) -----
__global__ __launch_bounds__(256) void compact_kernel(
        const int* __restrict__ slot_expert,
        const int* __restrict__ slot_keep,
        int* __restrict__ ecount,
        int* __restrict__ elist,
        int* __restrict__ slot_pos) {
    __shared__ int lcnt[NEXP];
    __shared__ int lbase[NEXP];
    const int tid = threadIdx.x;
    const int s = blockIdx.x * 256 + tid;
    if (tid < NEXP) lcnt[tid] = 0;
    __syncthreads();
    const int e  = slot_expert[s];
    const int kp = slot_keep[s];
    int lpos = 0;
    if (kp) lpos = atomicAdd(&lcnt[e], 1);
    __syncthreads();
    if (tid < NEXP) lbase[tid] = lcnt[tid] ? atomicAdd(&ecount[tid], lcnt[tid]) : 0;
    __syncthreads();
    if (kp) {
        int p = lbase[e] + lpos;
        elist[e * CAPE + p] = s;
        if (slot_pos) slot_pos[s] = e * CAPE + p;
    }
}

// ------- base (atomic-fallback path only): out[t] = (dropped g sum)*x[t] ---
__global__ void base_kernel(const float* __restrict__ x,
                            const int* __restrict__ keep,
                            const float* __restrict__ gate,
                            float* __restrict__ out) {
    int i = blockIdx.x * blockDim.x + threadIdx.x;   // float4 index
    int t = i >> 8;                                  // 256 float4 per row
    float c = 0.f;
    if (!keep[2 * t])     c += gate[2 * t];
    if (!keep[2 * t + 1]) c += gate[2 * t + 1];
    floatx4 v = ((const floatx4*)x)[i];
    ((floatx4*)out)[i] = v * c;
}

// ---------------- fp32 -> bf16 conversion (weights) ------------------------
__global__ void cvt_kernel(const float* __restrict__ src,
                           unsigned short* __restrict__ dst, int n4) {
    int i = blockIdx.x * blockDim.x + threadIdx.x;
    if (i >= n4) return;
    floatx4 v = ((const floatx4*)src)[i];
    ushort4v o;
    o[0] = f2bf(v[0]); o[1] = f2bf(v[1]); o[2] = f2bf(v[2]); o[3] = f2bf(v[3]);
    ((ushort4v*)dst)[i] = o;
}

// ---------------- grouped expert GEMM (m97 structure + XOR swizzle) --------
// grid (n=8, m=8, e=16), block 256 = 4 waves; 128x128 tile, BK=32.
// LDS k-block position for (row, kblock q) is q ^ ((row>>1)&3): makes the
// b128 fragment reads a perfect 2-way bank spread (free) instead of 8-way.
template <bool STORE_YS>
__global__ __launch_bounds__(256)
void moe_gemm(const unsigned short* __restrict__ Xb,
              const unsigned short* __restrict__ Wb,
              const float* __restrict__ eb,
              const int* __restrict__ elist,
              const int* __restrict__ ecount,
              const float* __restrict__ slot_gate,
              float* __restrict__ ys,
              float* __restrict__ out) {
    __shared__ unsigned short As[128 * 32];   // [row][kpos] 64 B rows, swizzled
    __shared__ unsigned short Bs[128 * 32];

    const int e  = blockIdx.z;
    const int ne = ecount[e];
    const int m0 = blockIdx.y * 128;
    if (m0 >= ne) return;
    const int n0   = blockIdx.x * 128;
    const int wv   = threadIdx.x >> 6;
    const int lane = threadIdx.x & 63;
    const int q    = lane >> 4;
    const int l15  = lane & 15;

    // --- per-lane global base pointers for staging (K-invariant) ---
    // lane L -> row ch*16 + L/4; loads global kblock j = (L&3) ^ ((L>>3)&3)
    // so that LDS position (L&3) holds kblock j, i.e. pos = j ^ ((row>>1)&3).
    const int jblk = (lane & 3) ^ ((lane >> 3) & 3);
    const unsigned short* gA[2];
    const unsigned short* gB[2];
    int chunk[2];
#pragma unroll
    for (int c = 0; c < 2; c++) {
        int ch = wv * 2 + c;
        chunk[c] = ch;
        int arow = ch * 16 + (lane >> 2);
        int m    = m0 + arow;
        int slot = elist[e * CAPE + (m < ne ? m : 0)];
        int tok  = slot >> 1;
        gA[c] = Xb + (size_t)tok * DIM + jblk * 8;
        int frow = n0 + arow;
        gB[c] = Wb + (size_t)e * DIM * DIM + (size_t)frow * DIM + jblk * 8;
    }

    const int wm = (wv & 1) * 64;
    const int wn = (wv >> 1) * 64;
    const int kswz = ((l15 >> 1) & 3);   // read-side swizzle for this lane's rows
    floatx4 acc[4][4] = {};

    for (int k0 = 0; k0 < DIM; k0 += 32) {
        __syncthreads();
#pragma unroll
        for (int c = 0; c < 2; c++) {
            GLOAD_LDS16(gA[c] + k0, &As[chunk[c] * 512]);
            GLOAD_LDS16(gB[c] + k0, &Bs[chunk[c] * 512]);
        }
        __syncthreads();

        short8 af[4], bf[4];
        const int koff = (q ^ kswz) * 8;
#pragma unroll
        for (int fi = 0; fi < 4; fi++)
            af[fi] = *(const short8*)&As[(wm + fi * 16 + l15) * 32 + koff];
#pragma unroll
        for (int fj = 0; fj < 4; fj++)
            bf[fj] = *(const short8*)&Bs[(wn + fj * 16 + l15) * 32 + koff];
#pragma unroll
        for (int fi = 0; fi < 4; fi++)
#pragma unroll
            for (int fj = 0; fj < 4; fj++)
                acc[fi][fj] = __builtin_amdgcn_mfma_f32_16x16x32_bf16(
                    af[fi], bf[fj], acc[fi][fj], 0, 0, 0);
    }

    // --- epilogue: C/D 16x16 layout col=lane&15, row=q*4+r ---
    float ebv[4];
#pragma unroll
    for (int fj = 0; fj < 4; fj++)
        ebv[fj] = eb[e * DIM + n0 + wn + fj * 16 + l15];
#pragma unroll
    for (int fi = 0; fi < 4; fi++) {
        const int mrow = m0 + wm + fi * 16 + q * 4;
#pragma unroll
        for (int r = 0; r < 4; r++) {
            int m = mrow + r;
            if (m >= ne) continue;
            if (STORE_YS) {
                float* yrow = ys + ((size_t)e * CAPE + m) * DIM + n0 + wn;
#pragma unroll
                for (int fj = 0; fj < 4; fj++)
                    yrow[fj * 16 + l15] = acc[fi][fj][r] + ebv[fj];
            } else {
                int slot = elist[e * CAPE + m];
                int tok  = slot >> 1;
                float g  = slot_gate[slot];
                float* orow = out + (size_t)tok * DIM + n0 + wn;
#pragma unroll
                for (int fj = 0; fj < 4; fj++)
                    atomicAdd(orow + fj * 16 + l15, g * (acc[fi][fj][r] + ebv[fj]));
            }
        }
    }
}

// ---------------- combine: out = sum_k g_k * (keep ? ys[pos] : x) ----------
__global__ void combine_kernel(const float* __restrict__ x,
                               const float* __restrict__ ys,
                               const int* __restrict__ keep,
                               const int* __restrict__ pos,
                               const float* __restrict__ gate,
                               float* __restrict__ out) {
    int i = blockIdx.x * 256 + threadIdx.x;   // float4 index
    int t = i >> 8;
    int c = i & 255;
    int s0 = 2 * t, s1 = s0 + 1;
    floatx4 xv = ((const floatx4*)x)[i];
    float g0 = gate[s0], g1 = gate[s1];
    floatx4 r;
    if (keep[s0]) {
        floatx4 y0 = ((const floatx4*)ys)[((size_t)pos[s0] << 8) + c];
        r = y0 * g0;
    } else r = xv * g0;
    if (keep[s1]) {
        floatx4 y1 = ((const floatx4*)ys)[((size_t)pos[s1] << 8) + c];
        r += y1 * g1;
    } else r += xv * g1;
    ((floatx4*)out)[i] = r;
}

extern "C" void kernel_launch(void* const* d_in, const int* in_sizes, int n_in,
                              void* d_out, int out_size, void* d_ws, size_t ws_size,
                              hipStream_t stream) {
    const float* x  = (const float*)d_in[0];   // [N, D]
    const float* gw = (const float*)d_in[1];   // [D, E]
    const float* gb = (const float*)d_in[2];   // [E]
    const float* ew = (const float*)d_in[3];   // [E, D, D]
    const float* eb = (const float*)d_in[4];   // [E, D]
    float* out = (float*)d_out;                // [N, D]

    char* ws = (char*)d_ws;
    // ---- workspace layout (bytes); proven through round 4 ----
    int* counts      = (int*)(ws + 0);                   //    64 B
    int* ecount      = (int*)(ws + 64);                  //    64 B
    int* slot_expert = (int*)(ws + 256);                 //  64 KB
    int* slot_keep   = (int*)(ws + 65792);               //  64 KB
    float* slot_gate = (float*)(ws + 131328);            //  64 KB
    unsigned long long* slot_key = (unsigned long long*)(ws + 196864);  // 128 KB
    unsigned long long* buckets  = (unsigned long long*)(ws + 327936);  //   2 MB
    int* elist       = (int*)(ws + 2425088);             //  64 KB
    float* gwT       = (float*)(ws + 2490624);           //  64 KB
    unsigned short* Xb = (unsigned short*)(ws + 2556160);   // 16 MB
    unsigned short* Wb = (unsigned short*)(ws + 19333376);  // 32 MB -> end 52887808
    int* slot_pos    = (int*)(ws + 52887808);            //  64 KB (ys path only)
    int* ecount2     = (int*)(ws + 52953088);            //  unused pad
    float* ys        = (float*)(ws + 52953344);          //  64 MB (ys path only)
    const size_t WS_NEED_YS = 52953344ull + (size_t)NEXP * CAPE * DIM * 4;  // ~114.5 MB

    const bool ys_path = (ws_size >= WS_NEED_YS);
    (void)ecount2;

    hipMemsetAsync(ws, 0, 256, stream);  // zero counts + ecount

    gwt_kernel <<<64, 256, 0, stream>>>(gw, gwT);
    gate_kernel<<<N_TOK / 4, 256, 0, stream>>>(x, gwT, gb, slot_expert, slot_key,
                                               slot_gate, Xb);
    bucket_kernel<<<NSLOT / 256, 256, 0, stream>>>(slot_expert, slot_key, counts, buckets);
    keep_wave_kernel<<<NSLOT / 4, 256, 0, stream>>>(slot_expert, slot_key, counts,
                                                    buckets, slot_keep);
    compact_kernel<<<NSLOT / 256, 256, 0, stream>>>(slot_expert, slot_keep, ecount, elist,
                                                    ys_path ? slot_pos : nullptr);
    cvt_kernel<<<(NEXP * DIM * DIM / 4) / 256, 256, 0, stream>>>(ew, Wb, NEXP * DIM * DIM / 4);

    if (ys_path) {
        moe_gemm<true><<<dim3(8, 8, 16), 256, 0, stream>>>(Xb, Wb, eb, elist, ecount,
                                                           slot_gate, ys, out);
        combine_kernel<<<N_TOK, 256, 0, stream>>>(x, ys, slot_keep, slot_pos,
                                                  slot_gate, out);
    } else {
        base_kernel<<<(N_TOK * DIM / 4) / 256, 256, 0, stream>>>(x, slot_keep,
                                                                 slot_gate, out);
        moe_gemm<false><<<dim3(8, 8, 16), 256, 0, stream>>>(Xb, Wb, eb, elist, ecount,
                                                            slot_gate, nullptr, out);
    }
}